// Round 1
// baseline (369.265 us; speedup 1.0000x reference)
//
#include <hip/hip_runtime.h>
#include <stdint.h>

#define B_   4
#define C_   256
#define W_   4096
#define DQK_ 32

typedef short bf16x8 __attribute__((ext_vector_type(8)));
typedef float f32x4  __attribute__((ext_vector_type(4)));

__device__ __forceinline__ float fexp2f(float x){
#if __has_builtin(__builtin_amdgcn_exp2f)
  return __builtin_amdgcn_exp2f(x);
#else
  return exp2f(x);
#endif
}
__device__ __forceinline__ float frcpf(float x){
#if __has_builtin(__builtin_amdgcn_rcpf)
  return __builtin_amdgcn_rcpf(x);
#else
  return 1.0f / x;
#endif
}
__device__ __forceinline__ unsigned short bf16rn(float f){
  union { float f; uint32_t u; } v; v.f = f;
  uint32_t u = v.u;
  u += 0x7FFFu + ((u >> 16) & 1u);
  return (unsigned short)(u >> 16);
}

// ---------------------------------------------------------------------------
// Kernel 1: projections q = wq@x0+bq, k = (wk@x1+bk)*scale*log2e  -> bf16
//           qT/kT layout [B][W][32] row-major (MFMA-fragment friendly),
//           plus x0 -> bf16 copy (x0b, [B][C][W]).
// grid (64, 4)  block 256 : 64 w per block, c split 4-ways across waves.
// ---------------------------------------------------------------------------
__global__ __launch_bounds__(256) void sa_prep(
    const float* __restrict__ x0, const float* __restrict__ x1,
    const float* __restrict__ wq, const float* __restrict__ bq,
    const float* __restrict__ wk, const float* __restrict__ bk,
    unsigned short* __restrict__ qT, unsigned short* __restrict__ kT,
    unsigned short* __restrict__ x0b)
{
  const int b    = blockIdx.y;
  const int wloc = threadIdx.x & 63;
  const int cq   = __builtin_amdgcn_readfirstlane((int)(threadIdx.x >> 6));
  const int w    = blockIdx.x * 64 + wloc;
  const size_t bw = (size_t)b * ((size_t)C_ * W_) + w;

  float accq[DQK_], acck[DQK_];
  #pragma unroll
  for (int d = 0; d < DQK_; ++d){ accq[d] = 0.f; acck[d] = 0.f; }

  const int c0 = cq * 64;
  for (int i = 0; i < 64; ++i){
    const int c = c0 + i;
    const size_t off = bw + (size_t)c * W_;
    const float v0 = x0[off];
    const float v1 = x1[off];
    x0b[off] = bf16rn(v0);
    #pragma unroll
    for (int d = 0; d < DQK_; ++d){
      accq[d] = fmaf(wq[d * C_ + c], v0, accq[d]);
      acck[d] = fmaf(wk[d * C_ + c], v1, acck[d]);
    }
  }

  __shared__ float red[4][64][DQK_ + 1];   // +1 pad: banks (w+d)%32, 2-way max
  #pragma unroll
  for (int d = 0; d < DQK_; ++d) red[cq][wloc][d] = accq[d];
  __syncthreads();
  if (cq == 0){
    uint32_t pk[DQK_ / 2];
    #pragma unroll
    for (int d = 0; d < DQK_; ++d){
      float s = red[0][wloc][d] + red[1][wloc][d] + red[2][wloc][d] + red[3][wloc][d] + bq[d];
      unsigned short h = bf16rn(s);
      if (d & 1) pk[d >> 1] |= ((uint32_t)h << 16);
      else       pk[d >> 1]  = h;
    }
    uint4* dst = (uint4*)(qT + ((size_t)b * W_ + w) * DQK_);
    #pragma unroll
    for (int j = 0; j < 4; ++j)
      dst[j] = make_uint4(pk[4*j], pk[4*j+1], pk[4*j+2], pk[4*j+3]);
  }
  __syncthreads();
  #pragma unroll
  for (int d = 0; d < DQK_; ++d) red[cq][wloc][d] = acck[d];
  __syncthreads();
  if (cq == 0){
    const float SCL = 0.0625f * 1.44269504088896340736f; // 1/sqrt(256) * log2(e)
    uint32_t pk[DQK_ / 2];
    #pragma unroll
    for (int d = 0; d < DQK_; ++d){
      float s = (red[0][wloc][d] + red[1][wloc][d] + red[2][wloc][d] + red[3][wloc][d] + bk[d]) * SCL;
      unsigned short h = bf16rn(s);
      if (d & 1) pk[d >> 1] |= ((uint32_t)h << 16);
      else       pk[d >> 1]  = h;
    }
    uint4* dst = (uint4*)(kT + ((size_t)b * W_ + w) * DQK_);
    #pragma unroll
    for (int j = 0; j < 4; ++j)
      dst[j] = make_uint4(pk[4*j], pk[4*j+1], pk[4*j+2], pk[4*j+3]);
  }
}

// ---------------------------------------------------------------------------
// Kernel 2: per (b, 64-row m-tile): energy (MFMA, K=32), 2-pass softmax
// (recompute energy in pass 2), write f32 attention, PV GEMM via MFMA with
// c as the D-row dim (coalesced [C][W] out writes), + gamma*pv + x1.
// grid 256 (XCD-swizzled: batch b -> XCDs {2b,2b+1}), block 256 (4 waves x 16 rows).
// ---------------------------------------------------------------------------
__global__ __launch_bounds__(256) void sa_attn(
    const unsigned short* __restrict__ qT, const unsigned short* __restrict__ kT,
    const unsigned short* __restrict__ x0b, const float* __restrict__ x1,
    const float* __restrict__ gamma,
    float* __restrict__ out, float* __restrict__ att)
{
  const int lb = blockIdx.x;
  const int rr = lb & 7, tt = lb >> 3;
  const int b = rr >> 1;
  const int mtile = (tt << 1) | (rr & 1);
  const int lane = threadIdx.x & 63;
  const int wid = __builtin_amdgcn_readfirstlane((int)(threadIdx.x >> 6));
  const int lr = lane & 15;
  const int lg = lane >> 4;
  const int m0 = mtile * 64 + wid * 16;

  // A-frag (energy): kT rows m0+lr, k-slice lg*8..lg*8+7  (16B contiguous)
  const bf16x8 kfrag = *(const bf16x8*)(kT + ((size_t)b * W_ + m0 + lr) * DQK_ + (size_t)lg * 8);
  const unsigned short* qb = qT + (size_t)b * W_ * DQK_;

  // ---- pass 1: per-lane online max/sum over this lane's column subset ----
  float pm[4], ps[4];
  #pragma unroll
  for (int r = 0; r < 4; ++r){ pm[r] = -3.0e38f; ps[r] = 0.f; }

  for (int n0 = 0; n0 < W_; n0 += 32){
    bf16x8 q0 = *(const bf16x8*)(qb + (size_t)(n0 + lr) * DQK_ + (size_t)lg * 8);
    bf16x8 q1 = *(const bf16x8*)(qb + (size_t)(n0 + 16 + lr) * DQK_ + (size_t)lg * 8);
    f32x4 e0 = __builtin_amdgcn_mfma_f32_16x16x32_bf16(kfrag, q0, (f32x4){0.f,0.f,0.f,0.f}, 0, 0, 0);
    f32x4 e1 = __builtin_amdgcn_mfma_f32_16x16x32_bf16(kfrag, q1, (f32x4){0.f,0.f,0.f,0.f}, 0, 0, 0);
    #pragma unroll
    for (int r = 0; r < 4; ++r){
      float ea = e0[r];
      if (ea > pm[r]){ ps[r] *= fexp2f(pm[r] - ea); pm[r] = ea; }
      ps[r] += fexp2f(ea - pm[r]);
      float eb = e1[r];
      if (eb > pm[r]){ ps[r] *= fexp2f(pm[r] - eb); pm[r] = eb; }
      ps[r] += fexp2f(eb - pm[r]);
    }
  }
  // combine (max,sum) across the 16 lanes sharing each row
  #pragma unroll
  for (int mask = 1; mask <= 8; mask <<= 1){
    #pragma unroll
    for (int r = 0; r < 4; ++r){
      float om = __shfl_xor(pm[r], mask);
      float os = __shfl_xor(ps[r], mask);
      float mn = fmaxf(pm[r], om);
      ps[r] = ps[r] * fexp2f(pm[r] - mn) + os * fexp2f(om - mn);
      pm[r] = mn;
    }
  }
  float invS[4];
  #pragma unroll
  for (int r = 0; r < 4; ++r) invS[r] = frcpf(ps[r]);

  // ---- pass 2: recompute energy, write attention, PV accumulate ----
  __shared__ __align__(16) unsigned short Alds[4][16][40]; // per-wave P tile, row pad 40 (80B)
  unsigned short* aw = &Alds[wid][0][0];

  f32x4 acc[16];
  #pragma unroll
  for (int ct = 0; ct < 16; ++ct) acc[ct] = (f32x4){0.f,0.f,0.f,0.f};

  const unsigned short* xb = x0b + (size_t)b * C_ * W_;
  float* attb = att + ((size_t)b * W_ + m0) * W_;

  for (int n0 = 0; n0 < W_; n0 += 32){
    bf16x8 q0 = *(const bf16x8*)(qb + (size_t)(n0 + lr) * DQK_ + (size_t)lg * 8);
    bf16x8 q1 = *(const bf16x8*)(qb + (size_t)(n0 + 16 + lr) * DQK_ + (size_t)lg * 8);
    f32x4 e0 = __builtin_amdgcn_mfma_f32_16x16x32_bf16(kfrag, q0, (f32x4){0.f,0.f,0.f,0.f}, 0, 0, 0);
    f32x4 e1 = __builtin_amdgcn_mfma_f32_16x16x32_bf16(kfrag, q1, (f32x4){0.f,0.f,0.f,0.f}, 0, 0, 0);
    #pragma unroll
    for (int r = 0; r < 4; ++r){
      const int row = lg * 4 + r;
      float p0 = fexp2f(e0[r] - pm[r]) * invS[r];
      float p1 = fexp2f(e1[r] - pm[r]) * invS[r];
      attb[(size_t)row * W_ + n0 + lr]      = p0;
      attb[(size_t)row * W_ + n0 + 16 + lr] = p1;
      aw[row * 40 + lr]      = bf16rn(p0);
      aw[row * 40 + 16 + lr] = bf16rn(p1);
    }
    // B-frag (PV): P[m=lr][n-slice lg*8..+7], 16B contiguous, shared by all 16 c-tiles
    bf16x8 afrag = *(const bf16x8*)(aw + lr * 40 + lg * 8);
    #pragma unroll
    for (int ct = 0; ct < 16; ++ct){
      // A-frag (PV): x0b rows c = ct*16+lr, n-slice lg*8..+7 (16B contiguous)
      bf16x8 xf = *(const bf16x8*)(xb + (size_t)(ct * 16 + lr) * W_ + n0 + (size_t)lg * 8);
      acc[ct] = __builtin_amdgcn_mfma_f32_16x16x32_bf16(xf, afrag, acc[ct], 0, 0, 0);
    }
  }

  // ---- epilogue: out[b][c][m] = gamma*pv + x1 ----
  const float g = gamma[0];
  const float* x1b = x1 + (size_t)b * C_ * W_;
  float* outb = out + (size_t)b * C_ * W_;
  #pragma unroll
  for (int ct = 0; ct < 16; ++ct){
    #pragma unroll
    for (int r = 0; r < 4; ++r){
      const int c = ct * 16 + lg * 4 + r;          // D row -> channel
      const size_t idx = (size_t)c * W_ + m0 + lr; // D col -> position (coalesced)
      outb[idx] = fmaf(g, acc[ct][r], x1b[idx]);
    }
  }
}

extern "C" void kernel_launch(void* const* d_in, const int* in_sizes, int n_in,
                              void* d_out, int out_size, void* d_ws, size_t ws_size,
                              hipStream_t stream)
{
  const float* x0    = (const float*)d_in[0];
  const float* x1    = (const float*)d_in[1];
  const float* wq    = (const float*)d_in[2];
  const float* bq    = (const float*)d_in[3];
  const float* wk    = (const float*)d_in[4];
  const float* bk    = (const float*)d_in[5];
  const float* gamma = (const float*)d_in[6];

  unsigned short* qT  = (unsigned short*)d_ws;                 // [B][W][32] bf16, 1 MB
  unsigned short* kT  = qT + (size_t)B_ * W_ * DQK_;           // 1 MB
  unsigned short* x0b = kT + (size_t)B_ * W_ * DQK_;           // [B][C][W] bf16, 8 MB

  float* out = (float*)d_out;                                  // [B][C][W]
  float* att = out + (size_t)B_ * C_ * W_;                     // [B][W][W]

  sa_prep<<<dim3(64, 4), 256, 0, stream>>>(x0, x1, wq, bq, wk, bk, qT, kT, x0b);
  sa_attn<<<256, 256, 0, stream>>>(qT, kT, x0b, x1, gamma, out, att);
}